// Round 7
// baseline (176.087 us; speedup 1.0000x reference)
//
#include <hip/hip_runtime.h>
#include <math.h>

#define NN 200000
#define DD 64
#define BB 4096
#define KK 128
#define WW 20
#define HH 128
#define TPB 1024
#define RPB 8    // targets per block

__device__ __forceinline__ float fast_rcp(float x) { return __builtin_amdgcn_rcpf(x); }
__device__ __forceinline__ float fast_rsq(float x) { return __builtin_amdgcn_rsqf(x); }

// Fully-fused pipeline, round 7: 512 blocks x 1024 threads (16 waves), 8
// targets/block -> 2 blocks/CU x 16 waves = 32 waves/CU (100% occupancy
// budget; R6's 512-thread version capped at 50%, measured 35%).
//   pre-A : 1 gather slot/thread; hws; waves 0-7 do target encodings.
//   phase1: 1 slot/thread, full 64-dim norm+att-dot in-lane (uniform s_load
//           params -- the R3-validated scheme), writes wk directly.
//   hist  : 1 (r,d) column/thread, 20-tap decay FMA into tile cols 0-127.
//   phase3: wave-PAIR per target (64 neighbors each), lane=dim, recompute +
//           FMA; combine via aggp.
//   GEMM  : thread = one (r,h) output; weight row streamed from global as
//           float4 (L1/L2-hot, vmcnt pipe) -- NO wl LDS staging, no per-chunk
//           barriers (R6 spent ~384 LDS ops/thread + 16 barriers here).
// 5 barriers total; feat4 tile never leaves LDS.
__global__ __launch_bounds__(1024, 8) void fused(
    const float* __restrict__ adj_time, const float* __restrict__ gc,
    const float* __restrict__ cur_time, const float* __restrict__ neigh_mask,
    const float* __restrict__ hist_feat, const float* __restrict__ hist_time,
    const float* __restrict__ t2v_w, const float* __restrict__ t2v_b,
    const float* __restrict__ node_w, const float* __restrict__ node_b,
    const float* __restrict__ att_w, const float* __restrict__ att_b,
    const float* __restrict__ weight,
    const int* __restrict__ targets, const int* __restrict__ neigh_idx,
    float* __restrict__ out)
{
    const int b0   = blockIdx.x * RPB;
    const int tid  = threadIdx.x;
    const int lane = tid & 63;
    const int wv   = tid >> 6;          // wave id 0..15

    __shared__ float2 dtg[RPB * KK];    // {dt, g} per (target, neighbor)   8 KB
    __shared__ float  wk[RPB * KK];     // per-neighbor weight              4 KB
    __shared__ float  hws[RPB][WW];     // history decay weights          640 B
    __shared__ float  stL[RPB];         // target att-dot per row
    __shared__ float  tile[RPB * 256];  // feat4 rows                       8 KB
    __shared__ float  aggp[16][64];     // phase-3 wave partials            4 KB

    const float t = cur_time[0];

    // ---- pre-A: gathers (1 slot/thread) ----
    float ts_k, m_k;
    {
        int   slot = tid;                           // slot = r*128 + k
        int   idx  = neigh_idx[b0 * KK + slot];
        m_k        = neigh_mask[b0 * KK + slot];
        float at   = adj_time[idx];
        float g    = gc[idx];
        dtg[slot]  = make_float2(fabsf(t - at), g);
        ts_k       = fast_rcp(2.0f * __logf(2.71828182845904523536f + (t - at)));
    }
    // ---- pre-A: history decay weights ----
    if (tid < RPB * WW) {
        int r = tid / WW, w = tid - r * WW;
        hws[r][w] = fast_rcp(2.0f * (1.0f + (t - hist_time[(b0 + r) * WW + w])));
    }
    // ---- pre-A: target encoding, waves 0-7 -> target wv ----
    if (wv < RPB) {
        int   tg  = targets[b0 + wv];
        float dtT = fabsf(t - adj_time[tg]);
        float gT  = gc[tg];
        float ph  = fmaf(t2v_w[lane], dtT, t2v_b[lane]);
        float tv_ = (lane == 0) ? ph : __cosf(ph);
        float f   = fmaxf(tv_ + fmaf(gT, node_w[lane], node_b[lane]), 0.f);
        float ss  = f * f;
#pragma unroll
        for (int off = 32; off; off >>= 1) ss += __shfl_xor(ss, off, 64);
        float invn = fast_rsq(fmaxf(ss, 1e-24f));
        float tfn  = f * invn;
        float sdt  = tfn * att_w[lane];
#pragma unroll
        for (int off = 32; off; off >>= 1) sdt += __shfl_xor(sdt, off, 64);
        if (lane == 0) stL[wv] = sdt;
        tile[wv * 256 + 128 + lane] = tfn;
    }
    __syncthreads();   // A: dtg, hws, stL ready

    // ---- phase 1: full 64-dim in-lane per slot; params via literal-offset s_loads ----
    {
        const float ab = att_b[0];
        int    slot = tid;
        int    r    = slot >> 7;
        float2 dg   = dtg[slot];
        float  s2 = 0.f, sd = 0.f;
#pragma unroll 8
        for (int d = 0; d < 64; ++d) {
            float ph  = fmaf(t2v_w[d], dg.x, t2v_b[d]);
            float cv  = __cosf(ph);
            float tv_ = (d == 0) ? ph : cv;
            float f   = fmaxf(tv_ + fmaf(dg.y, node_w[d], node_b[d]), 0.f);
            s2 = fmaf(f, f, s2);
            sd = fmaf(f, att_w[64 + d], sd);
        }
        float invn = fast_rsq(fmaxf(s2, 1e-24f));
        float sc   = ts_k + stL[r] + sd * invn + ab;
        sc = (sc > 0.f) ? sc : 0.01f * sc;          // leaky_relu(0.01)
        wk[slot] = sc * m_k * invn;
    }

    // ---- history aggregation into tile cols 0-127 (1 column/thread) ----
    {
        int r = tid >> 7, d = tid & 127;
        const float* hf = hist_feat + (size_t)(b0 + r) * WW * 128 + d;
        float s = 0.f;
#pragma unroll
        for (int w = 0; w < WW; ++w) s = fmaf(hws[r][w], hf[w * 128], s);
        tile[r * 256 + d] = s;
    }
    __syncthreads();   // C: wk ready

    // ---- phase 3: wave-pair per target; lane = dim; recompute + FMA ----
    {
        const int r   = wv >> 1;
        const int sub = wv & 1;
        float pw = t2v_w[lane], pb = t2v_b[lane];
        float nw = node_w[lane], nb2 = node_b[lane];
        float acc = 0.f;
        const int base = r * KK + sub * 64;
#pragma unroll 8
        for (int k = 0; k < 64; ++k) {
            float2 dg = dtg[base + k];              // uniform addr -> broadcast
            float  w_ = wk[base + k];
            float  ph = fmaf(pw, dg.x, pb);
            float  cv = __cosf(ph);
            float  tv_ = (lane == 0) ? ph : cv;
            float  f  = fmaxf(tv_ + fmaf(dg.y, nw, nb2), 0.f);
            acc = fmaf(w_, f, acc);
        }
        aggp[wv][lane] = acc;
    }
    __syncthreads();   // D

    if ((wv & 1) == 0) {
        int r = wv >> 1;
        tile[r * 256 + 192 + lane] = aggp[wv][lane] + aggp[wv + 1][lane];
    }
    __syncthreads();   // E: tile complete

    // ---- GEMM: thread = (r = tid>>7, h = tid&127); one 256-dot per thread ----
    {
        const int h = tid & 127;
        const int r = tid >> 7;
        const float4* wrow = (const float4*)(weight + (size_t)h * 256);
        const float4* tb   = (const float4*)(tile + r * 256);
        float acc = 0.f;
#pragma unroll 8
        for (int j = 0; j < 64; ++j) {
            float4 w4 = wrow[j];                    // global, L1/L2-hot
            float4 f4 = tb[j];                      // LDS broadcast (r uniform/wave)
            acc += w4.x * f4.x + w4.y * f4.y + w4.z * f4.z + w4.w * f4.w;
        }
        out[(size_t)(b0 + r) * 128 + h] = fmaxf(acc, 0.f);
    }
}

extern "C" void kernel_launch(void* const* d_in, const int* in_sizes, int n_in,
                              void* d_out, int out_size, void* d_ws, size_t ws_size,
                              hipStream_t stream) {
    const float* adj_time  = (const float*)d_in[0];
    const float* gc        = (const float*)d_in[1];
    const float* cur_time  = (const float*)d_in[2];
    const float* neigh_mask= (const float*)d_in[3];
    const float* hist_feat = (const float*)d_in[4];
    const float* hist_time = (const float*)d_in[5];
    const float* t2v_w     = (const float*)d_in[6];
    const float* t2v_b     = (const float*)d_in[7];
    const float* node_w    = (const float*)d_in[8];
    const float* node_b    = (const float*)d_in[9];
    const float* att_w     = (const float*)d_in[10];
    const float* att_b     = (const float*)d_in[11];
    const float* weight    = (const float*)d_in[12];
    const int*   targets   = (const int*)d_in[13];
    const int*   neigh_idx = (const int*)d_in[14];

    float* out = (float*)d_out;

    fused<<<BB / RPB, TPB, 0, stream>>>(adj_time, gc, cur_time, neigh_mask,
                                        hist_feat, hist_time, t2v_w, t2v_b,
                                        node_w, node_b, att_w, att_b, weight,
                                        targets, neigh_idx, out);
}

// Round 8
// 138.552 us; speedup vs baseline: 1.2709x; 1.2709x over previous
//
#include <hip/hip_runtime.h>
#include <math.h>

#define NN 200000
#define DD 64
#define BB 4096
#define KK 128
#define WW 20
#define HH 128
#define TPB 512
#define RPB 4    // targets per block

__device__ __forceinline__ float fast_rcp(float x) { return __builtin_amdgcn_rcpf(x); }
__device__ __forceinline__ float fast_rsq(float x) { return __builtin_amdgcn_rsqf(x); }

// Fully-fused pipeline, round 8: R6's exact phase structure (which measured
// fused=42us), with the only change being RPB 8->4 at constant TPB=512:
// grid 512->1024 blocks = 4 blocks/CU x 8 waves = 32 waves/CU (100% budget;
// R6 was grid-capped at 50%, measured 35%). GEMM keeps the R6-validated
// LDS-staged wl (pad-33, conflict-free) -- R7 proved per-output global weight
// streaming is L1-thrash latency-bound (VALUBusy 28%).
//   pre-A : 1 gather slot/thread; hws; waves 0-3 target encodings.
//   phase1: 1 slot/thread, full 64-dim norm+att-dot in-lane (uniform s_load
//           params), writes wk directly.
//   hist  : 1 (r,d) column/thread, 20-tap decay FMA into tile cols 0-127.
//   phase3: wave-pair per target (64 neighbors each), lane=dim, recompute +
//           FMA; combine via aggp.
//   GEMM  : thread = one (r,h) output; W chunk-staged in LDS (pad-33).
__global__ __launch_bounds__(512, 8) void fused(
    const float* __restrict__ adj_time, const float* __restrict__ gc,
    const float* __restrict__ cur_time, const float* __restrict__ neigh_mask,
    const float* __restrict__ hist_feat, const float* __restrict__ hist_time,
    const float* __restrict__ t2v_w, const float* __restrict__ t2v_b,
    const float* __restrict__ node_w, const float* __restrict__ node_b,
    const float* __restrict__ att_w, const float* __restrict__ att_b,
    const float* __restrict__ weight,
    const int* __restrict__ targets, const int* __restrict__ neigh_idx,
    float* __restrict__ out)
{
    const int b0   = blockIdx.x * RPB;
    const int tid  = threadIdx.x;
    const int lane = tid & 63;
    const int wv   = tid >> 6;          // wave id 0..7

    __shared__ float2 dtg[RPB * KK];    // {dt, g} per (target, neighbor)   4 KB
    __shared__ float  wk[RPB * KK];     // per-neighbor weight              2 KB
    __shared__ float  hws[RPB][WW];     // history decay weights          320 B
    __shared__ float  stL[RPB];         // target att-dot per row
    __shared__ float  tile[RPB * 256];  // feat4 rows                       4 KB
    __shared__ float  aggp[8][64];      // phase-3 wave partials            2 KB
    __shared__ float  wl[128 * 33];     // W chunk [128 h][32 j], pad 33  ~17 KB

    const float t = cur_time[0];

    // ---- pre-A: gathers (1 slot/thread) ----
    float ts_k, m_k;
    {
        int   slot = tid;                           // slot = r*128 + k
        int   idx  = neigh_idx[b0 * KK + slot];
        m_k        = neigh_mask[b0 * KK + slot];
        float at   = adj_time[idx];
        float g    = gc[idx];
        dtg[slot]  = make_float2(fabsf(t - at), g);
        ts_k       = fast_rcp(2.0f * __logf(2.71828182845904523536f + (t - at)));
    }
    // ---- pre-A: history decay weights ----
    if (tid < RPB * WW) {
        int r = tid / WW, w = tid - r * WW;
        hws[r][w] = fast_rcp(2.0f * (1.0f + (t - hist_time[(b0 + r) * WW + w])));
    }
    // ---- pre-A: target encoding, waves 0-3 -> target wv ----
    if (wv < RPB) {
        int   tg  = targets[b0 + wv];
        float dtT = fabsf(t - adj_time[tg]);
        float gT  = gc[tg];
        float ph  = fmaf(t2v_w[lane], dtT, t2v_b[lane]);
        float tv_ = (lane == 0) ? ph : __cosf(ph);
        float f   = fmaxf(tv_ + fmaf(gT, node_w[lane], node_b[lane]), 0.f);
        float ss  = f * f;
#pragma unroll
        for (int off = 32; off; off >>= 1) ss += __shfl_xor(ss, off, 64);
        float invn = fast_rsq(fmaxf(ss, 1e-24f));
        float tfn  = f * invn;
        float sdt  = tfn * att_w[lane];
#pragma unroll
        for (int off = 32; off; off >>= 1) sdt += __shfl_xor(sdt, off, 64);
        if (lane == 0) stL[wv] = sdt;
        tile[wv * 256 + 128 + lane] = tfn;
    }
    __syncthreads();   // A: dtg, hws, stL ready

    // ---- phase 1: full 64-dim in-lane per slot; params via literal-offset s_loads ----
    {
        const float ab = att_b[0];
        int    slot = tid;
        int    r    = slot >> 7;
        float2 dg   = dtg[slot];
        float  s2 = 0.f, sd = 0.f;
#pragma unroll 8
        for (int d = 0; d < 64; ++d) {
            float ph  = fmaf(t2v_w[d], dg.x, t2v_b[d]);
            float cv  = __cosf(ph);
            float tv_ = (d == 0) ? ph : cv;
            float f   = fmaxf(tv_ + fmaf(dg.y, node_w[d], node_b[d]), 0.f);
            s2 = fmaf(f, f, s2);
            sd = fmaf(f, att_w[64 + d], sd);
        }
        float invn = fast_rsq(fmaxf(s2, 1e-24f));
        float sc   = ts_k + stL[r] + sd * invn + ab;
        sc = (sc > 0.f) ? sc : 0.01f * sc;          // leaky_relu(0.01)
        wk[slot] = sc * m_k * invn;
    }

    // ---- history aggregation into tile cols 0-127 (1 column/thread) ----
    {
        int r = tid >> 7, d = tid & 127;
        const float* hf = hist_feat + (size_t)(b0 + r) * WW * 128 + d;
        float s = 0.f;
#pragma unroll
        for (int w = 0; w < WW; ++w) s = fmaf(hws[r][w], hf[w * 128], s);
        tile[r * 256 + d] = s;
    }
    __syncthreads();   // C: wk ready

    // ---- phase 3: wave-pair per target; lane = dim; recompute + FMA ----
    {
        const int r   = wv >> 1;
        const int sub = wv & 1;
        float pw = t2v_w[lane], pb = t2v_b[lane];
        float nw = node_w[lane], nb2 = node_b[lane];
        float acc = 0.f;
        const int base = r * KK + sub * 64;
#pragma unroll 8
        for (int k = 0; k < 64; ++k) {
            float2 dg = dtg[base + k];              // uniform addr -> broadcast
            float  w_ = wk[base + k];
            float  ph = fmaf(pw, dg.x, pb);
            float  cv = __cosf(ph);
            float  tv_ = (lane == 0) ? ph : cv;
            float  f  = fmaxf(tv_ + fmaf(dg.y, nw, nb2), 0.f);
            acc = fmaf(w_, f, acc);
        }
        aggp[wv][lane] = acc;
    }
    __syncthreads();   // D

    if ((wv & 1) == 0) {
        int r = wv >> 1;
        tile[r * 256 + 192 + lane] = aggp[wv][lane] + aggp[wv + 1][lane];
    }

    // ---- GEMM: thread = (r = tid>>7, h = tid&127); one 256-dot per thread ----
    const int h = tid & 127;
    const int r = tid >> 7;
    const float* tb = tile + r * 256;
    float acc = 0.f;

    for (int c = 0; c < 8; ++c) {
        __syncthreads();   // c=0: covers tile writes; else: wl reuse
#pragma unroll
        for (int i = 0; i < 8; ++i) {
            int l  = i * TPB + tid;
            int hh = l >> 5, jj = l & 31;
            wl[hh * 33 + jj] = weight[hh * 256 + c * 32 + jj];
        }
        __syncthreads();

#pragma unroll
        for (int jj = 0; jj < 32; jj += 4) {
            float w0 = wl[h * 33 + jj + 0];
            float w1 = wl[h * 33 + jj + 1];
            float w2 = wl[h * 33 + jj + 2];
            float w3 = wl[h * 33 + jj + 3];
            float4 f4 = *(const float4*)(tb + c * 32 + jj);
            acc += w0 * f4.x + w1 * f4.y + w2 * f4.z + w3 * f4.w;
        }
    }

    out[(size_t)(b0 + r) * 128 + h] = fmaxf(acc, 0.f);
}

extern "C" void kernel_launch(void* const* d_in, const int* in_sizes, int n_in,
                              void* d_out, int out_size, void* d_ws, size_t ws_size,
                              hipStream_t stream) {
    const float* adj_time  = (const float*)d_in[0];
    const float* gc        = (const float*)d_in[1];
    const float* cur_time  = (const float*)d_in[2];
    const float* neigh_mask= (const float*)d_in[3];
    const float* hist_feat = (const float*)d_in[4];
    const float* hist_time = (const float*)d_in[5];
    const float* t2v_w     = (const float*)d_in[6];
    const float* t2v_b     = (const float*)d_in[7];
    const float* node_w    = (const float*)d_in[8];
    const float* node_b    = (const float*)d_in[9];
    const float* att_w     = (const float*)d_in[10];
    const float* att_b     = (const float*)d_in[11];
    const float* weight    = (const float*)d_in[12];
    const int*   targets   = (const int*)d_in[13];
    const int*   neigh_idx = (const int*)d_in[14];

    float* out = (float*)d_out;

    fused<<<BB / RPB, TPB, 0, stream>>>(adj_time, gc, cur_time, neigh_mask,
                                        hist_feat, hist_time, t2v_w, t2v_b,
                                        node_w, node_b, att_w, att_b, weight,
                                        targets, neigh_idx, out);
}

// Round 9
// 137.867 us; speedup vs baseline: 1.2772x; 1.0050x over previous
//
#include <hip/hip_runtime.h>
#include <math.h>

#define NN 200000
#define DD 64
#define BB 4096
#define KK 128
#define WW 20
#define HH 128
#define TPB 512
#define RPB 4    // targets per block

__device__ __forceinline__ float fast_rcp(float x) { return __builtin_amdgcn_rcpf(x); }
__device__ __forceinline__ float fast_rsq(float x) { return __builtin_amdgcn_rsqf(x); }
// Wave-broadcast of lane l's value via v_readlane (VALU/SALU pipe, NOT the
// per-CU LDS pipe). R8 analysis: the kernel is LDS-pipe throughput bound
// (~3700 ds-cycles/wave x 32 waves/CU ~= the measured 43us), so every
// LDS op moved to readlane is a direct win.
__device__ __forceinline__ float readlane_f(float v, int l) {
    return __builtin_bit_cast(float, __builtin_amdgcn_readlane(__builtin_bit_cast(int, v), l));
}

// Fully-fused pipeline, round 9. TPB=512, RPB=4, grid 1024 (4 blocks/CU).
// LDS-pipe diet vs R8:
//   - dtg[]/wk[] LDS arrays DELETED: wave wv's phase-3 neighbors are exactly
//     the slots its own lanes gathered in pre-A (slot == tid), and wk is
//     computed by the same thread -> phase 3 uses readlane broadcasts.
//   - GEMM: wl chunk staged/read as float4 (pad-36 rows: bank-start 4h mod 32,
//     quarter-wave 2-way = free); tile row held in registers (1 b128 preload
//     covers 256 floats across 64 lanes) and fetched per j-step via readlane.
// ds-ops/wave ~1200 cyc (was ~3700).
__global__ __launch_bounds__(512, 8) void fused(
    const float* __restrict__ adj_time, const float* __restrict__ gc,
    const float* __restrict__ cur_time, const float* __restrict__ neigh_mask,
    const float* __restrict__ hist_feat, const float* __restrict__ hist_time,
    const float* __restrict__ t2v_w, const float* __restrict__ t2v_b,
    const float* __restrict__ node_w, const float* __restrict__ node_b,
    const float* __restrict__ att_w, const float* __restrict__ att_b,
    const float* __restrict__ weight,
    const int* __restrict__ targets, const int* __restrict__ neigh_idx,
    float* __restrict__ out)
{
    const int b0   = blockIdx.x * RPB;
    const int tid  = threadIdx.x;
    const int lane = tid & 63;
    const int wv   = tid >> 6;          // wave id 0..7
    const int r_   = tid >> 7;          // target row 0..3 (wave-uniform)
    const int d_   = tid & 127;

    __shared__ float hws[RPB][WW];      // history decay weights          320 B
    __shared__ float stL[RPB];          // target att-dot per row
    __shared__ float tile[RPB * 256];   // feat4 rows                       4 KB
    __shared__ float aggp[8][64];       // phase-3 wave partials            2 KB
    __shared__ float wl[128 * 36];      // W chunk [128 h][32 j] pad 36    18 KB

    const float t = cur_time[0];

    // ---- pre-A: every thread gathers its own neighbor slot (slot = tid) ----
    float m_k, at, g, dt, ts_k;
    {
        int idx = neigh_idx[b0 * KK + tid];
        m_k     = neigh_mask[b0 * KK + tid];
        at      = adj_time[idx];
        g       = gc[idx];
        dt      = fabsf(t - at);
        ts_k    = fast_rcp(2.0f * __logf(2.71828182845904523536f + (t - at)));
    }
    if (tid < RPB * WW) {
        int r = tid / WW, w = tid - r * WW;
        hws[r][w] = fast_rcp(2.0f * (1.0f + (t - hist_time[(b0 + r) * WW + w])));
    }
    if (wv < RPB) {                     // target encoding, wave wv -> target wv
        int   tg  = targets[b0 + wv];
        float dtT = fabsf(t - adj_time[tg]);
        float gT  = gc[tg];
        float ph  = fmaf(t2v_w[lane], dtT, t2v_b[lane]);
        float tv_ = (lane == 0) ? ph : __cosf(ph);
        float f   = fmaxf(tv_ + fmaf(gT, node_w[lane], node_b[lane]), 0.f);
        float ss  = f * f;
#pragma unroll
        for (int off = 32; off; off >>= 1) ss += __shfl_xor(ss, off, 64);
        float invn = fast_rsq(fmaxf(ss, 1e-24f));
        float tfn  = f * invn;
        float sdt  = tfn * att_w[lane];
#pragma unroll
        for (int off = 32; off; off >>= 1) sdt += __shfl_xor(sdt, off, 64);
        if (lane == 0) stL[wv] = sdt;
        tile[wv * 256 + 128 + lane] = tfn;
    }
    __syncthreads();   // A: hws + stL ready

    // ---- phase 1: full 64-dim norm+att-dot in-lane; wk stays in a register ----
    float wk;
    {
        float s2 = 0.f, sd = 0.f;
#pragma unroll 8
        for (int d = 0; d < 64; ++d) {
            float ph  = fmaf(t2v_w[d], dt, t2v_b[d]);   // uniform -> s_load
            float cv  = __cosf(ph);
            float tv_ = (d == 0) ? ph : cv;
            float f   = fmaxf(tv_ + fmaf(g, node_w[d], node_b[d]), 0.f);
            s2 = fmaf(f, f, s2);
            sd = fmaf(f, att_w[64 + d], sd);
        }
        float invn = fast_rsq(fmaxf(s2, 1e-24f));
        float sc   = ts_k + stL[r_] + sd * invn + att_b[0];
        sc = (sc > 0.f) ? sc : 0.01f * sc;              // leaky_relu(0.01)
        wk = sc * m_k * invn;
    }

    // ---- history aggregation into tile cols 0-127 ----
    {
        const float* hf = hist_feat + (size_t)(b0 + r_) * WW * 128 + d_;
        float s = 0.f;
#pragma unroll
        for (int w = 0; w < WW; ++w) s = fmaf(hws[r_][w], hf[w * 128], s);
        tile[r_ * 256 + d_] = s;
    }

    // ---- phase 3: lane = dim; neighbor j's {dt,g,wk} via readlane (no LDS) ----
    {
        float pw = t2v_w[lane], pb = t2v_b[lane];
        float nw = node_w[lane], nb2 = node_b[lane];
        float acc = 0.f;
#pragma unroll
        for (int j = 0; j < 64; ++j) {
            float dtj = readlane_f(dt, j);
            float gj  = readlane_f(g,  j);
            float wkj = readlane_f(wk, j);
            float ph  = fmaf(pw, dtj, pb);
            float cv  = __cosf(ph);
            float tv_ = (lane == 0) ? ph : cv;
            float f   = fmaxf(tv_ + fmaf(gj, nw, nb2), 0.f);
            acc = fmaf(wkj, f, acc);
        }
        aggp[wv][lane] = acc;
    }
    __syncthreads();   // D

    if (!(wv & 1))
        tile[(wv >> 1) * 256 + 192 + lane] = aggp[wv][lane] + aggp[wv | 1][lane];
    __syncthreads();   // E: tile complete

    // ---- GEMM: thread = (r_, h); tile row register-resident across the wave ----
    const int h = tid & 127;
    float4 t4 = *(const float4*)(tile + r_ * 256 + 4 * lane);  // one-time preload
    float acc = 0.f;

    for (int c = 0; c < 8; ++c) {
        __syncthreads();   // protects wl overwrite
#pragma unroll
        for (int i = 0; i < 2; ++i) {
            int l  = i * TPB + tid;         // float4 index 0..1023
            int hh = l >> 3;
            int q8 = (l & 7) * 4;
            float4 w4 = *(const float4*)(weight + hh * 256 + c * 32 + q8);
            *(float4*)(wl + hh * 36 + q8) = w4;
        }
        __syncthreads();

#pragma unroll
        for (int q = 0; q < 8; ++q) {
            float4 w4 = *(const float4*)(wl + h * 36 + 4 * q);
            int src = c * 8 + q;            // lane holding tile[r_][4src..4src+3]
            float tx = readlane_f(t4.x, src);
            float ty = readlane_f(t4.y, src);
            float tz = readlane_f(t4.z, src);
            float tw = readlane_f(t4.w, src);
            acc += w4.x * tx + w4.y * ty + w4.z * tz + w4.w * tw;
        }
    }

    out[(size_t)(b0 + r_) * 128 + h] = fmaxf(acc, 0.f);
}

extern "C" void kernel_launch(void* const* d_in, const int* in_sizes, int n_in,
                              void* d_out, int out_size, void* d_ws, size_t ws_size,
                              hipStream_t stream) {
    const float* adj_time  = (const float*)d_in[0];
    const float* gc        = (const float*)d_in[1];
    const float* cur_time  = (const float*)d_in[2];
    const float* neigh_mask= (const float*)d_in[3];
    const float* hist_feat = (const float*)d_in[4];
    const float* hist_time = (const float*)d_in[5];
    const float* t2v_w     = (const float*)d_in[6];
    const float* t2v_b     = (const float*)d_in[7];
    const float* node_w    = (const float*)d_in[8];
    const float* node_b    = (const float*)d_in[9];
    const float* att_w     = (const float*)d_in[10];
    const float* att_b     = (const float*)d_in[11];
    const float* weight    = (const float*)d_in[12];
    const int*   targets   = (const int*)d_in[13];
    const int*   neigh_idx = (const int*)d_in[14];

    float* out = (float*)d_out;

    fused<<<BB / RPB, TPB, 0, stream>>>(adj_time, gc, cur_time, neigh_mask,
                                        hist_feat, hist_time, t2v_w, t2v_b,
                                        node_w, node_b, att_w, att_b, weight,
                                        targets, neigh_idx, out);
}

// Round 10
// 137.495 us; speedup vs baseline: 1.2807x; 1.0027x over previous
//
#include <hip/hip_runtime.h>
#include <math.h>

#define NN 200000
#define DD 64
#define BB 4096
#define KK 128
#define WW 20
#define HH 128
#define TPB 512
#define RPB 4        // targets per block
#define TSTRIDE 260  // tile row stride: 260 mod 32 = 4 -> r-rows staggered 4 banks

__device__ __forceinline__ float fast_rcp(float x) { return __builtin_amdgcn_rcpf(x); }
__device__ __forceinline__ float fast_rsq(float x) { return __builtin_amdgcn_rsqf(x); }
__device__ __forceinline__ float readlane_f(float v, int l) {
    return __builtin_bit_cast(float, __builtin_amdgcn_readlane(__builtin_bit_cast(int, v), l));
}

// Round 10. TPB=512, RPB=4, grid 1024 (4 blocks/CU). Changes vs R9 (which was
// VALU-issue + barrier-idle bound: 62% VALUBusy, 16 GEMM barriers, 256
// readlanes/thread in GEMM):
//   - GEMM restructured barrier-free: thread = (h = wv*16 + lane>>2, r =
//     lane&3). W float4 read straight from global (quad-merged, 16 segments
//     per inst = minimal; footprint 16KB/wave streamed once, L2-hot -- NOT
//     R7's 64-distinct-row thrash). tile read = LDS b128 at 4 distinct
//     addrs/wave, conflict-free via stride-260 padding. No wl staging, no
//     readlanes, no per-chunk barriers (19 -> 3 total).
//   - phase-1 d==0 select hoisted to a prologue.
__global__ __launch_bounds__(512, 8) void fused(
    const float* __restrict__ adj_time, const float* __restrict__ gc,
    const float* __restrict__ cur_time, const float* __restrict__ neigh_mask,
    const float* __restrict__ hist_feat, const float* __restrict__ hist_time,
    const float* __restrict__ t2v_w, const float* __restrict__ t2v_b,
    const float* __restrict__ node_w, const float* __restrict__ node_b,
    const float* __restrict__ att_w, const float* __restrict__ att_b,
    const float* __restrict__ weight,
    const int* __restrict__ targets, const int* __restrict__ neigh_idx,
    float* __restrict__ out)
{
    const int b0   = blockIdx.x * RPB;
    const int tid  = threadIdx.x;
    const int lane = tid & 63;
    const int wv   = tid >> 6;          // wave id 0..7
    const int r_   = tid >> 7;          // target row 0..3 (wave-uniform)
    const int d_   = tid & 127;

    __shared__ float hws[RPB][WW];          // history decay weights
    __shared__ float stL[RPB];              // target att-dot per row
    __shared__ float tile[RPB * TSTRIDE];   // feat4 rows (padded)
    __shared__ float aggp[8][64];           // phase-3 wave partials

    const float t = cur_time[0];

    // ---- pre-A: every thread gathers its own neighbor slot (slot = tid) ----
    float m_k, g, dt, ts_k;
    {
        int idx = neigh_idx[b0 * KK + tid];
        m_k     = neigh_mask[b0 * KK + tid];
        float a = adj_time[idx];
        g       = gc[idx];
        dt      = fabsf(t - a);
        ts_k    = fast_rcp(2.0f * __logf(2.71828182845904523536f + (t - a)));
    }
    if (tid < RPB * WW) {
        int r = tid / WW, w = tid - r * WW;
        hws[r][w] = fast_rcp(2.0f * (1.0f + (t - hist_time[(b0 + r) * WW + w])));
    }
    if (wv < RPB) {                     // target encoding, wave wv -> target wv
        int   tg  = targets[b0 + wv];
        float dtT = fabsf(t - adj_time[tg]);
        float gT  = gc[tg];
        float ph  = fmaf(t2v_w[lane], dtT, t2v_b[lane]);
        float tv_ = (lane == 0) ? ph : __cosf(ph);
        float f   = fmaxf(tv_ + fmaf(gT, node_w[lane], node_b[lane]), 0.f);
        float ss  = f * f;
#pragma unroll
        for (int off = 32; off; off >>= 1) ss += __shfl_xor(ss, off, 64);
        float invn = fast_rsq(fmaxf(ss, 1e-24f));
        float tfn  = f * invn;
        float sdt  = tfn * att_w[lane];
#pragma unroll
        for (int off = 32; off; off >>= 1) sdt += __shfl_xor(sdt, off, 64);
        if (lane == 0) stL[wv] = sdt;
        tile[wv * TSTRIDE + 128 + lane] = tfn;
    }
    __syncthreads();   // A: hws + stL ready

    // ---- phase 1: 64-dim norm+att-dot in-lane; d=0 hoisted; wk in register ----
    float wk;
    {
        // d = 0: tv = ph (linear channel)
        float ph0 = fmaf(t2v_w[0], dt, t2v_b[0]);
        float f0  = fmaxf(ph0 + fmaf(g, node_w[0], node_b[0]), 0.f);
        float s2  = f0 * f0;
        float sd  = f0 * att_w[64];
#pragma unroll 9
        for (int d = 1; d < 64; ++d) {
            float ph = fmaf(t2v_w[d], dt, t2v_b[d]);   // uniform -> s_load
            float f  = fmaxf(__cosf(ph) + fmaf(g, node_w[d], node_b[d]), 0.f);
            s2 = fmaf(f, f, s2);
            sd = fmaf(f, att_w[64 + d], sd);
        }
        float invn = fast_rsq(fmaxf(s2, 1e-24f));
        float sc   = ts_k + stL[r_] + sd * invn + att_b[0];
        sc = (sc > 0.f) ? sc : 0.01f * sc;             // leaky_relu(0.01)
        wk = sc * m_k * invn;
    }

    // ---- history aggregation into tile cols 0-127 ----
    {
        const float* hf = hist_feat + (size_t)(b0 + r_) * WW * 128 + d_;
        float s = 0.f;
#pragma unroll
        for (int w = 0; w < WW; ++w) s = fmaf(hws[r_][w], hf[w * 128], s);
        tile[r_ * TSTRIDE + d_] = s;
    }

    // ---- phase 3: lane = dim; neighbor j's {dt,g,wk} via readlane (own wave) ----
    {
        float pw = t2v_w[lane], pb = t2v_b[lane];
        float nw = node_w[lane], nb2 = node_b[lane];
        float acc = 0.f;
#pragma unroll
        for (int j = 0; j < 64; ++j) {
            float dtj = readlane_f(dt, j);
            float gj  = readlane_f(g,  j);
            float wkj = readlane_f(wk, j);
            float ph  = fmaf(pw, dtj, pb);
            float cv  = __cosf(ph);
            float tv_ = (lane == 0) ? ph : cv;
            float f   = fmaxf(tv_ + fmaf(gj, nw, nb2), 0.f);
            acc = fmaf(wkj, f, acc);
        }
        aggp[wv][lane] = acc;
    }
    __syncthreads();   // D

    if (!(wv & 1))
        tile[(wv >> 1) * TSTRIDE + 192 + lane] = aggp[wv][lane] + aggp[wv | 1][lane];
    __syncthreads();   // E: tile complete

    // ---- GEMM (barrier-free): thread = (h = wv*16 + lane>>2, r = lane&3) ----
    {
        const int h = wv * 16 + (lane >> 2);
        const int r = lane & 3;
        const float4* wrow = (const float4*)(weight + (size_t)h * 256);
        const float*  tb   = tile + r * TSTRIDE;
        float acc = 0.f;
#pragma unroll 8
        for (int j = 0; j < 64; ++j) {
            float4 w4 = wrow[j];                       // global, quad-merged, L2-hot
            float4 f4 = *(const float4*)(tb + 4 * j);  // LDS b128, 4 addrs/wave, pad-free
            acc += w4.x * f4.x + w4.y * f4.y + w4.z * f4.z + w4.w * f4.w;
        }
        out[(size_t)(b0 + r) * 128 + h] = fmaxf(acc, 0.f);
    }
}

extern "C" void kernel_launch(void* const* d_in, const int* in_sizes, int n_in,
                              void* d_out, int out_size, void* d_ws, size_t ws_size,
                              hipStream_t stream) {
    const float* adj_time  = (const float*)d_in[0];
    const float* gc        = (const float*)d_in[1];
    const float* cur_time  = (const float*)d_in[2];
    const float* neigh_mask= (const float*)d_in[3];
    const float* hist_feat = (const float*)d_in[4];
    const float* hist_time = (const float*)d_in[5];
    const float* t2v_w     = (const float*)d_in[6];
    const float* t2v_b     = (const float*)d_in[7];
    const float* node_w    = (const float*)d_in[8];
    const float* node_b    = (const float*)d_in[9];
    const float* att_w     = (const float*)d_in[10];
    const float* att_b     = (const float*)d_in[11];
    const float* weight    = (const float*)d_in[12];
    const int*   targets   = (const int*)d_in[13];
    const int*   neigh_idx = (const int*)d_in[14];

    float* out = (float*)d_out;

    fused<<<BB / RPB, TPB, 0, stream>>>(adj_time, gc, cur_time, neigh_mask,
                                        hist_feat, hist_time, t2v_w, t2v_b,
                                        node_w, node_b, att_w, att_b, weight,
                                        targets, neigh_idx, out);
}